// Round 7
// baseline (259.367 us; speedup 1.0000x reference)
//
#include <hip/hip_runtime.h>
#include <hip/hip_bf16.h>

#define B_NUM 4096
#define N_NUM 2048
#define E_NUM 1638
#define OUT_NUM 512
#define NTOT 2560   // N_NUM + OUT_NUM
#define KDIM 2048
#define NKT 32      // K tiles of 64

typedef unsigned short u16;
typedef __attribute__((ext_vector_type(8))) __bf16 bf16x8;
typedef __attribute__((ext_vector_type(4))) float f32x4;

__device__ __forceinline__ u16 f2bf(float f) {
  union { float f; unsigned u; } v; v.f = f;
  unsigned r = v.u + 0x7fffu + ((v.u >> 16) & 1u);
  return (u16)(r >> 16);
}

__device__ __forceinline__ void gload16(const u16* src, u16* dst) {
  __builtin_amdgcn_global_load_lds((__attribute__((address_space(1))) void*)src,
                                   (__attribute__((address_space(3))) void*)dst,
                                   16, 0, 0);
}

#define BAR() do { asm volatile("" ::: "memory"); \
                   __builtin_amdgcn_s_barrier();  \
                   asm volatile("" ::: "memory"); } while (0)

// ---------------- prep_u: u = relu(0.9*x + 0.1*(i + b)) ----------------
__global__ __launch_bounds__(256) void prep_u(const float* __restrict__ in_i,
                                              const float* __restrict__ in_x,
                                              const float* __restrict__ bias,
                                              float* __restrict__ u_f32,
                                              u16* __restrict__ u_bf16) {
  const int t = blockIdx.x * 256 + threadIdx.x;
  const int e = t * 4;
  const float4 iv = *(const float4*)(in_i + e);
  const float4 xv = *(const float4*)(in_x + e);
  const float4 bv = *(const float4*)(bias + (e & (N_NUM - 1)));
  float4 u;
  u.x = fmaxf(0.f, 0.9f * xv.x + 0.1f * (iv.x + bv.x));
  u.y = fmaxf(0.f, 0.9f * xv.y + 0.1f * (iv.y + bv.y));
  u.z = fmaxf(0.f, 0.9f * xv.z + 0.1f * (iv.z + bv.z));
  u.w = fmaxf(0.f, 0.9f * xv.w + 0.1f * (iv.w + bv.w));
  *(float4*)(u_f32 + e) = u;
  ushort4 ub;
  ub.x = f2bf(u.x); ub.y = f2bf(u.y); ub.z = f2bf(u.z); ub.w = f2bf(u.w);
  *(ushort4*)(u_bf16 + e) = ub;
}

// ---------------- prep_w: Wt[n][k] = signs[k]*|W[k][n]|, transposed, bf16 --
__global__ __launch_bounds__(256) void prep_w(const float* __restrict__ r,
                                              const float* __restrict__ f,
                                              u16* __restrict__ wt) {
  __shared__ u16 ldsT[64][72];
  const int k0 = blockIdx.y * 64;
  const int n0 = blockIdx.x * 64;
  const int tid = threadIdx.x;
  const int rloc = tid >> 4;
  const int c4 = (tid & 15) * 4;
#pragma unroll
  for (int rr = 0; rr < 4; ++rr) {
    const int kl = rr * 16 + rloc;
    const int k = k0 + kl;
    const float sign = (k < E_NUM) ? 1.f : -1.f;
    float4 v;
    if (n0 < N_NUM) v = *(const float4*)(r + k * N_NUM + n0 + c4);
    else            v = *(const float4*)(f + k * OUT_NUM + (n0 - N_NUM) + c4);
    float vals[4] = {v.x, v.y, v.z, v.w};
#pragma unroll
    for (int j = 0; j < 4; ++j) {
      float val = sign * fabsf(vals[j]);
      if (n0 < N_NUM && (n0 + c4 + j) == k) val = 0.f;
      ldsT[c4 + j][kl] = f2bf(val);
    }
  }
  __syncthreads();
  const int nl = tid >> 2;
  const int kc = (tid & 3) * 16;
  u16* dst = wt + (n0 + nl) * KDIM + k0 + kc;
  *(uint4*)(dst) = *(const uint4*)&ldsT[nl][kc];
  *(uint4*)(dst + 8) = *(const uint4*)&ldsT[nl][kc + 8];
}

// ---------------- gemm4d: 128x128, BK=64, 4 waves; A from GLOBAL ---------
// C = U[4096x2048] @ Wt^T.  Diagnosis (R3 counters + m134 constants): the
// LDS pipe was the saturated resource (~1900 cyc/CU/K-tile vs MFMA 1030).
// Fix: A-fragments (8 k-contiguous bf16 = 16 B aligned) load DIRECTLY from
// global (L2/L3-resident) into VGPRs, register-double-buffered (afA/afB).
// Only B goes through LDS (R3's proven swizzled pipeline, 2x16 KiB).
// Per K-tile T (buf c = T&1; entry: AFC=A(T) ready, buf[c]=B(T) landed,
// in-flight = B(T+1) 4 loads):
//   RD_B(buf c) 8x ds_read_b128; LOAD_A(T+1)->AFN 8x global_dwordx4
//   setprio1; 16 MFMA ks=0; lgkmcnt(0); BAR   // all waves done with buf[c]
//   STB B(T+2)->buf[c]; 16 MFMA ks=1; setprio0
//   vmcnt(4)  // retire A(T+1)+B(T+1) (12 oldest), keep B(T+2); BAR
// Tail: Tn/Tb clamp to NKT-1; clamped stages write only dead buffers
// (after the mid-BAR all reads of the target drained), clamped A dead.
__global__ __launch_bounds__(256, 2) void gemm4d(const u16* __restrict__ U,
                                                 const u16* __restrict__ Wt,
                                                 float* __restrict__ out) {
  __shared__ u16 lds[2][128 * 64];  // B only, [dbuf][col-major-row x k], 32 KiB
  const int t = threadIdx.x;
  const int w = t >> 6, lane = t & 63;
  const int lr = lane & 15, lg = lane >> 4;
  const int wm = w >> 1, wn = w & 1;       // 2x2 wave grid, wave tile 64x64
  const int row0 = blockIdx.y * 128;
  const int col0 = blockIdx.x * 128;

  // B staging: thread t covers phys LDS u16 offset i*2048 + t*8
  const int srow = t >> 3;                              // 0..31
  const int koff = 8 * ((t & 7) ^ (srow & 7));          // pre-swizzled src col
  const u16* bS = Wt + (col0 + srow) * KDIM + koff;
  const int stBase = w * 512;                           // wave-uniform base

  // B fragment reads (swizzled)
  const int brow = wn * 64 + lr;
  const int xs = (lr & 7) << 4;
  const int ca0 = ((lg * 16) ^ xs) >> 1;        // k-slice 0 (u16 index)
  const int ca1 = ((64 + lg * 16) ^ xs) >> 1;   // k-slice 1

  // A direct-load base: lane reads U[row0+wm*64+mi*16+lr][kt*64+ks*32+lg*8]
  const u16* aF = U + (size_t)(row0 + wm * 64 + lr) * KDIM + lg * 8;

  f32x4 acc[4][4] = {};
  bf16x8 afA[4][2], afB[4][2], bf[4][2];

#define STB(c, kt) { const u16* g_ = bS + (kt) * 64;                        \
  _Pragma("unroll") for (int i_ = 0; i_ < 4; ++i_)                          \
    gload16(g_ + i_ * 32 * KDIM, &lds[c][i_ * 2048 + stBase]); }
#define LOAD_A(dst, kt) { _Pragma("unroll") for (int mi = 0; mi < 4; ++mi) {\
    dst[mi][0] = *(const bf16x8*)(aF + mi * 16 * KDIM + (kt) * 64);         \
    dst[mi][1] = *(const bf16x8*)(aF + mi * 16 * KDIM + (kt) * 64 + 32); } }
#define RD_B(c) { _Pragma("unroll") for (int ni = 0; ni < 4; ++ni) {        \
    bf[ni][0] = *(const bf16x8*)&lds[c][(brow + ni * 16) * 64 + ca0];       \
    bf[ni][1] = *(const bf16x8*)&lds[c][(brow + ni * 16) * 64 + ca1]; } }
#define MFMA_KS(AF, ks) { _Pragma("unroll") for (int mi = 0; mi < 4; ++mi)  \
    _Pragma("unroll") for (int ni = 0; ni < 4; ++ni)                        \
      acc[mi][ni] = __builtin_amdgcn_mfma_f32_16x16x32_bf16(                \
          AF[mi][ks], bf[ni][ks], acc[mi][ni], 0, 0, 0); }

#define KTILE(c, AFC, AFN, Tn, Tb) {                                        \
    RD_B(c);                                                                \
    LOAD_A(AFN, Tn);                                                        \
    __builtin_amdgcn_s_setprio(1);                                          \
    MFMA_KS(AFC, 0);                                                        \
    __builtin_amdgcn_sched_barrier(0);                                      \
    asm volatile("s_waitcnt lgkmcnt(0)" ::: "memory");                      \
    __builtin_amdgcn_sched_barrier(0);                                      \
    __builtin_amdgcn_s_barrier();                                           \
    STB(c, Tb);                                                             \
    MFMA_KS(AFC, 1);                                                        \
    __builtin_amdgcn_s_setprio(0);                                          \
    asm volatile("s_waitcnt vmcnt(4)" ::: "memory");                        \
    __builtin_amdgcn_sched_barrier(0);                                      \
    __builtin_amdgcn_s_barrier(); }

  // prologue: B(0)->buf0, A(0)->afA, B(1)->buf1; retire B(0)+A(0)
  STB(0, 0);
  LOAD_A(afA, 0);
  STB(1, 1);
  asm volatile("s_waitcnt vmcnt(4)" ::: "memory");
  __builtin_amdgcn_sched_barrier(0);
  BAR();

  for (int it = 0; it < NKT / 2; ++it) {
    const int T = 2 * it;
    const int t1 = (T + 1 < NKT) ? T + 1 : NKT - 1;
    const int t2 = (T + 2 < NKT) ? T + 2 : NKT - 1;
    const int t3 = (T + 3 < NKT) ? T + 3 : NKT - 1;
    KTILE(0, afA, afB, t1, t2);   // tile T:   reads buf0; stages B(T+2)->buf0
    KTILE(1, afB, afA, t2, t3);   // tile T+1: reads buf1; stages B(T+3)->buf1
  }
  asm volatile("s_waitcnt vmcnt(0)" ::: "memory");  // drain DMA before exit

  // epilogue: C/D map col=lane&15, row=(lane>>4)*4+q
  const int orow = row0 + wm * 64 + lg * 4;
  const int ocol = col0 + wn * 64 + lr;
  if (col0 < N_NUM) {           // whole tile -> r_out (2048 % 128 == 0)
    float* ro = out + B_NUM * OUT_NUM;
#pragma unroll
    for (int mi = 0; mi < 4; ++mi)
#pragma unroll
      for (int ni = 0; ni < 4; ++ni)
#pragma unroll
        for (int q = 0; q < 4; ++q)
          ro[(orow + mi * 16 + q) * N_NUM + ocol + ni * 16] = acc[mi][ni][q];
  } else {                      // whole tile -> f_out
#pragma unroll
    for (int mi = 0; mi < 4; ++mi)
#pragma unroll
      for (int ni = 0; ni < 4; ++ni)
#pragma unroll
        for (int q = 0; q < 4; ++q)
          out[(orow + mi * 16 + q) * OUT_NUM + (ocol - N_NUM) + ni * 16] = acc[mi][ni][q];
  }
#undef STB
#undef LOAD_A
#undef RD_B
#undef MFMA_KS
#undef KTILE
}

extern "C" void kernel_launch(void* const* d_in, const int* in_sizes, int n_in,
                              void* d_out, int out_size, void* d_ws, size_t ws_size,
                              hipStream_t stream) {
  const float* i_ = (const float*)d_in[0];
  const float* x  = (const float*)d_in[1];
  const float* r  = (const float*)d_in[2];
  const float* f  = (const float*)d_in[3];
  const float* b  = (const float*)d_in[4];
  float* out = (float*)d_out;

  u16* U  = (u16*)d_ws;                                      // 16 MB
  u16* Wt = (u16*)((char*)d_ws + (size_t)B_NUM * KDIM * 2);  // 10 MB

  float* u_region = out + (size_t)B_NUM * OUT_NUM + (size_t)B_NUM * N_NUM;

  prep_u<<<(B_NUM * N_NUM / 4) / 256, 256, 0, stream>>>(i_, x, b, u_region, U);
  prep_w<<<dim3(NTOT / 64, N_NUM / 64), 256, 0, stream>>>(r, f, Wt);
  gemm4d<<<dim3(NTOT / 128, B_NUM / 128), 256, 0, stream>>>(U, Wt, out);
}